// Round 1
// baseline (292.284 us; speedup 1.0000x reference)
//
#include <hip/hip_runtime.h>
#include <math.h>

#define BB 256
#define LL 500
#define EE 300
#define NROWS (BB * LL)      // 128000
#define NJ 18                // 3 (aw3) + 1 (cw3) + 5 (aw5) + 1 (cw5) + 7 (aw7) + 1 (cw7)
#define NC 75                // float4 chunks per row (300/4)
#define CB 5                 // chunks per batch (75 = 15*5 exact)
#define NB 15                // batches
#define DR 256               // dot rows per block = 250 outputs + 6 halo
#define TOUT 250             // outputs per block -> 2 tiles cover L=500 exactly
#define XB4 (DR * CB)        // 1280 float4 per x buffer (20 KB)

// ---------------------------------------------------------------------------
// R7 rewrite: reduction-free mapping + pipelined LDS x-stream.
// Old design was latency-bound (VALUBusy 23%, occ 19%, HBM 13%): 2304 blocks
// convoying through serial load->vmcnt(0)->compute phases, plus a 288-op
// butterfly per wave. Now: 512 blocks (exactly 2/CU, one residency round),
// each thread owns 2 complete rows x 9 dots (no cross-lane reduce at all),
// x double-buffered through LDS in 15 chunk-batches with next-batch global
// loads issued under the current batch's FMAs (T14 async split). Weight
// reads are wave-uniform LDS broadcasts; x LDS stride 80 B is bank-even.
// dlds aliases the dead x-buffer to keep LDS at 61.6 KB -> 2 blocks/CU.
// ---------------------------------------------------------------------------
__global__ __launch_bounds__(256) void fused_kernel(
    const float* __restrict__ x,
    const float* __restrict__ aw3, const float* __restrict__ ab3,
    const float* __restrict__ cw3, const float* __restrict__ cb3,
    const float* __restrict__ aw5, const float* __restrict__ ab5,
    const float* __restrict__ cw5, const float* __restrict__ cb5,
    const float* __restrict__ aw7, const float* __restrict__ ab7,
    const float* __restrict__ cw7, const float* __restrict__ cb7,
    float* __restrict__ out)
{
    __shared__ float4 wlds[NJ * NC];     // 1350 f4 = 21.6 KB, layout [d][75]
    __shared__ float4 xbuf[2][XB4];      // 2 x 20 KB, layout [row][5] per batch
    float* dlds = (float*)&xbuf[0][0];   // [DR][NJ+1] floats = 19456 B, aliased

    const int tid = threadIdx.x;
    const int b   = blockIdx.x >> 1;
    const int t   = blockIdx.x & 1;
    const int l0  = t * TOUT - 3;        // global l of local dot-row 0

    // ---- staging slots: thread covers L = q*256+tid -> (row=L/5, cc=L%5) ----
    // (5-lane 80 B contiguous runs per row; row pointers clamped, invalid rows
    //  produce garbage dots that get zeroed by vf at the dlds write)
    const float4* xp[5];
#pragma unroll
    for (int q = 0; q < 5; ++q) {
        const int L   = q * 256 + tid;
        const int row = L / CB;
        const int cc  = L - row * CB;
        int g = l0 + row;
        g = g < 0 ? 0 : (g >= LL ? LL - 1 : g);
        xp[q] = (const float4*)(x + ((size_t)b * LL + g) * EE) + cc;
    }

    // issue batch-0 x loads first (oldest in the vmcnt queue)
    float4 xn[5];
#pragma unroll
    for (int q = 0; q < 5; ++q) xn[q] = xp[q][0];

    // ---- cooperative weight staging: 6 contiguous segments ----
    {
        const float4* s3a = (const float4*)aw3;   // 225
        const float4* s3c = (const float4*)cw3;   // 75
        const float4* s5a = (const float4*)aw5;   // 375
        const float4* s5c = (const float4*)cw5;   // 75
        const float4* s7a = (const float4*)aw7;   // 525
        const float4* s7c = (const float4*)cw7;   // 75
        for (int i = tid; i < 225; i += 256) wlds[i]        = s3a[i];
        for (int i = tid; i < 75;  i += 256) wlds[225 + i]  = s3c[i];
        for (int i = tid; i < 375; i += 256) wlds[300 + i]  = s5a[i];
        for (int i = tid; i < 75;  i += 256) wlds[675 + i]  = s5c[i];
        for (int i = tid; i < 525; i += 256) wlds[750 + i]  = s7a[i];
        for (int i = tid; i < 75;  i += 256) wlds[1275 + i] = s7c[i];
    }

    // batch 0 -> xbuf[0]
#pragma unroll
    for (int q = 0; q < 5; ++q) xbuf[0][q * 256 + tid] = xn[q];

    __syncthreads();

    // ---- compute mapping: wave pair splits d (9+9), lane owns 2 rows ----
    const int wav   = tid >> 6;
    const int lane  = tid & 63;
    const int dbase = (wav >> 1) * 9;          // waves 0,1 -> d 0..8; 2,3 -> 9..17
    const int rbase = (wav & 1) * 128 + lane;  // rows rbase and rbase+64

    float vf0, vf1;
    { const int g0 = l0 + rbase;      vf0 = (g0 >= 0 && g0 < LL) ? 1.0f : 0.0f; }
    { const int g1 = l0 + rbase + 64; vf1 = (g1 >= 0 && g1 < LL) ? 1.0f : 0.0f; }

    float acc[9][2];
#pragma unroll
    for (int dd = 0; dd < 9; ++dd) { acc[dd][0] = 0.0f; acc[dd][1] = 0.0f; }

#pragma unroll 1
    for (int s = 0; s < NB; ++s) {
        // prefetch batch s+1 into regs: ~900 cycles of FMA below hide the HBM trip
        if (s < NB - 1) {
#pragma unroll
            for (int q = 0; q < 5; ++q) { xp[q] += CB; xn[q] = xp[q][0]; }
        }

        const float4* xb = &xbuf[s & 1][rbase * CB];        // + (320*rr + cc) imm
        const float4* wb = &wlds[dbase * NC + s * CB];      // + (75*dd + cc) imm

#pragma unroll
        for (int cc = 0; cc < CB; ++cc) {
            const float4 x0 = xb[cc];
            const float4 x1 = xb[64 * CB + cc];
#pragma unroll
            for (int dd = 0; dd < 9; ++dd) {
                const float4 w = wb[dd * NC + cc];
                acc[dd][0] = fmaf(x0.w, w.w, fmaf(x0.z, w.z, fmaf(x0.y, w.y, fmaf(x0.x, w.x, acc[dd][0]))));
                acc[dd][1] = fmaf(x1.w, w.w, fmaf(x1.z, w.z, fmaf(x1.y, w.y, fmaf(x1.x, w.x, acc[dd][1]))));
            }
        }

        // write prefetched batch into the other buffer (vmcnt wait lands here,
        // mostly satisfied); barrier publishes it and retires this batch's reads
        if (s < NB - 1) {
#pragma unroll
            for (int q = 0; q < 5; ++q) xbuf[(s + 1) & 1][q * 256 + tid] = xn[q];
        }
        __syncthreads();
    }

    // ---- dots -> dlds (aliases xbuf; safe: all x reads retired at last barrier)
#pragma unroll
    for (int dd = 0; dd < 9; ++dd) {
        dlds[rbase * (NJ + 1) + dbase + dd]        = acc[dd][0] * vf0;
        dlds[(rbase + 64) * (NJ + 1) + dbase + dd] = acc[dd][1] * vf1;
    }
    __syncthreads();

    // ---- epilogue: thread = output index, all 3 branches ----
    if (tid < TOUT) {
        const int c = tid + 3;                 // local dot-row of the center
        const int r = b * LL + t * TOUT + tid;
        {
            float pre = 0.0f;
#pragma unroll
            for (int tp = 0; tp < 3; ++tp) pre += dlds[(c + tp - 1) * (NJ + 1) + tp];
            const float sg = 1.0f / (1.0f + expf(-(pre + ab3[0])));
            out[r] = tanhf(sg * dlds[c * (NJ + 1) + 3] + cb3[0]);
        }
        {
            float pre = 0.0f;
#pragma unroll
            for (int tp = 0; tp < 5; ++tp) pre += dlds[(c + tp - 2) * (NJ + 1) + 4 + tp];
            const float sg = 1.0f / (1.0f + expf(-(pre + ab5[0])));
            out[NROWS + r] = tanhf(sg * dlds[c * (NJ + 1) + 9] + cb5[0]);
        }
        {
            float pre = 0.0f;
#pragma unroll
            for (int tp = 0; tp < 7; ++tp) pre += dlds[(c + tp - 3) * (NJ + 1) + 10 + tp];
            const float sg = 1.0f / (1.0f + expf(-(pre + ab7[0])));
            out[2 * NROWS + r] = tanhf(sg * dlds[c * (NJ + 1) + 17] + cb7[0]);
        }
    }
}

extern "C" void kernel_launch(void* const* d_in, const int* in_sizes, int n_in,
                              void* d_out, int out_size, void* d_ws, size_t ws_size,
                              hipStream_t stream) {
    const float* x   = (const float*)d_in[0];
    const float* aw3 = (const float*)d_in[1];
    const float* ab3 = (const float*)d_in[2];
    const float* cw3 = (const float*)d_in[3];
    const float* cb3 = (const float*)d_in[4];
    const float* aw5 = (const float*)d_in[5];
    const float* ab5 = (const float*)d_in[6];
    const float* cw5 = (const float*)d_in[7];
    const float* cb5 = (const float*)d_in[8];
    const float* aw7 = (const float*)d_in[9];
    const float* ab7 = (const float*)d_in[10];
    const float* cw7 = (const float*)d_in[11];
    const float* cb7 = (const float*)d_in[12];

    float* out = (float*)d_out;  // [out3 | out5 | out7]

    // 256 batches x 2 l-tiles of 250 outputs; 512 blocks = exactly 2/CU
    fused_kernel<<<BB * 2, 256, 0, stream>>>(
        x, aw3, ab3, cw3, cb3, aw5, ab5, cw5, cb5, aw7, ab7, cw7, cb7, out);
}

// Round 2
// 246.714 us; speedup vs baseline: 1.1847x; 1.1847x over previous
//
#include <hip/hip_runtime.h>
#include <math.h>

#define BB 256
#define LL 500
#define EE 300
#define NROWS (BB * LL)      // 128000
#define NJ 18                // 3 (aw3) + 1 (cw3) + 5 (aw5) + 1 (cw5) + 7 (aw7) + 1 (cw7)
#define NC 75                // float4 chunks per row
#define TOUT 56              // outputs per tile
#define GRP 3                // blocks per batch
#define NT 3                 // tiles per block (GRP*NT = 9 tiles cover L=500)
#define DROWS 64             // dot rows per tile = TOUT + 6 halo (+2 spare)

// ---------------------------------------------------------------------------
// R8 = R6 (89us, proven) + two targeted fixes from the counter model:
//  (a) 16-lane butterfly via DPP (quad_perm xor1/xor2 + row_ror:4/8) instead
//      of __shfl_xor: 288 ds_swizzle/wave-tile move off the LDS pipe (R6's
//      largest LDS consumer, ~1700cy/wave-tile) onto the idle VALU.
//  (b) 3 tiles per block, weights staged once; next-tile x loads issued into
//      the SAME xall regs right after their last FMA use, and ALL barriers
//      are raw s_barrier + lgkmcnt(0) only -- global loads stay in flight
//      across barriers (counted-vmcnt idiom) instead of being drained by
//      __syncthreads' vmcnt(0). Memory overlaps butterfly+epilogue+next tile.
// R7 lesson: keep x in registers (LDS x-stream = 8-way conflicts + spills).
// ---------------------------------------------------------------------------

__device__ __forceinline__ float red16(float v) {
    // sum across each aligned 16-lane group, VALU-only (no LDS pipe):
    // xor1, xor2 via quad_perm; then rotate-by-4 and rotate-by-8 within the
    // 16-lane DPP row (rotation covers all quads for a commutative sum).
    int t;
    t = __builtin_amdgcn_update_dpp(0, __float_as_int(v), 0xB1, 0xF, 0xF, true); // quad_perm [1,0,3,2]
    v += __int_as_float(t);
    t = __builtin_amdgcn_update_dpp(0, __float_as_int(v), 0x4E, 0xF, 0xF, true); // quad_perm [2,3,0,1]
    v += __int_as_float(t);
    t = __builtin_amdgcn_update_dpp(0, __float_as_int(v), 0x124, 0xF, 0xF, true); // row_ror:4
    v += __int_as_float(t);
    t = __builtin_amdgcn_update_dpp(0, __float_as_int(v), 0x128, 0xF, 0xF, true); // row_ror:8
    v += __int_as_float(t);
    return v;
}

__device__ __forceinline__ void lds_fence_barrier() {
    // publish own LDS ops, cross the barrier, but leave global loads in flight
    asm volatile("s_waitcnt lgkmcnt(0)" ::: "memory");
    __builtin_amdgcn_s_barrier();
    asm volatile("" ::: "memory");   // no LDS op hoists above the barrier
}

__global__ __launch_bounds__(256) void fused_kernel(
    const float* __restrict__ x,
    const float* __restrict__ aw3, const float* __restrict__ ab3,
    const float* __restrict__ cw3, const float* __restrict__ cb3,
    const float* __restrict__ aw5, const float* __restrict__ ab5,
    const float* __restrict__ cw5, const float* __restrict__ cb5,
    const float* __restrict__ aw7, const float* __restrict__ ab7,
    const float* __restrict__ cw7, const float* __restrict__ cb7,
    float* __restrict__ out)
{
    __shared__ float4 wlds[NJ * NC];         // 1350 float4 = 21.6 KB
    __shared__ float dlds[DROWS][NJ + 1];    // stride 19, conflict-free (4.9 KB)

    const int tid = threadIdx.x;

    // ---- cooperative weight staging (oldest vmem in the queue) ----
    {
        const float4* s3a = (const float4*)aw3;   // 225
        const float4* s3c = (const float4*)cw3;   // 75
        const float4* s5a = (const float4*)aw5;   // 375
        const float4* s5c = (const float4*)cw5;   // 75
        const float4* s7a = (const float4*)aw7;   // 525
        const float4* s7c = (const float4*)cw7;   // 75
        for (int i = tid; i < 225; i += 256) wlds[i]        = s3a[i];
        for (int i = tid; i < 75;  i += 256) wlds[225 + i]  = s3c[i];
        for (int i = tid; i < 375; i += 256) wlds[300 + i]  = s5a[i];
        for (int i = tid; i < 75;  i += 256) wlds[675 + i]  = s5c[i];
        for (int i = tid; i < 525; i += 256) wlds[750 + i]  = s7a[i];
        for (int i = tid; i < 75;  i += 256) wlds[1275 + i] = s7c[i];
    }

    const int b    = blockIdx.x / GRP;
    const int grp  = blockIdx.x % GRP;
    const int wave = tid >> 6;               // 0..3
    const int lane = tid & 63;
    const int g    = lane >> 4;              // 0..3
    const int j    = lane & 15;              // 0..15
    const int lr   = wave * 16 + g * 4;      // local dot-row base (0..60)

    const float* xbb = x + (size_t)b * LL * EE;

    // ---- tile-0 x prefetch: all 20 float4 per lane (clamped rows) ----
    float4 xall[5][4];
    {
        const int l0 = (grp * NT) * TOUT - 3;
#pragma unroll
        for (int rr = 0; rr < 4; ++rr) {
            const int l  = l0 + lr + rr;
            const int lc = l < 0 ? 0 : (l >= LL ? LL - 1 : l);
            const float4* xr = (const float4*)(xbb + (size_t)lc * EE);
#pragma unroll
            for (int k = 0; k < 5; ++k) {
                const int c = (k == 4) ? ((j < 11) ? (j + 64) : 74) : (j + 16 * k);
                xall[k][rr] = xr[c];
            }
        }
    }

    // weights published; tile-0 x loads remain in flight across the barrier
    lds_fence_barrier();

#pragma unroll 1
    for (int tt = 0; tt < NT; ++tt) {
        const int t  = grp * NT + tt;
        const int l0 = t * TOUT - 3;

        float vf[4];
#pragma unroll
        for (int rr = 0; rr < 4; ++rr) {
            const int l = l0 + lr + rr;
            vf[rr] = (l >= 0 && l < LL) ? 1.0f : 0.0f;
        }

        float acc[NJ][4];
#pragma unroll
        for (int d = 0; d < NJ; ++d)
#pragma unroll
            for (int rr = 0; rr < 4; ++rr) acc[d][rr] = 0.0f;

#define COMPUTE(k, c)                                                               \
    {                                                                               \
        _Pragma("unroll")                                                           \
        for (int d = 0; d < NJ; ++d) {                                              \
            const float4 w = wlds[d * NC + (c)];                                    \
            acc[d][0] = fmaf(xall[k][0].w, w.w, fmaf(xall[k][0].z, w.z, fmaf(xall[k][0].y, w.y, fmaf(xall[k][0].x, w.x, acc[d][0])))); \
            acc[d][1] = fmaf(xall[k][1].w, w.w, fmaf(xall[k][1].z, w.z, fmaf(xall[k][1].y, w.y, fmaf(xall[k][1].x, w.x, acc[d][1])))); \
            acc[d][2] = fmaf(xall[k][2].w, w.w, fmaf(xall[k][2].z, w.z, fmaf(xall[k][2].y, w.y, fmaf(xall[k][2].x, w.x, acc[d][2])))); \
            acc[d][3] = fmaf(xall[k][3].w, w.w, fmaf(xall[k][3].z, w.z, fmaf(xall[k][3].y, w.y, fmaf(xall[k][3].x, w.x, acc[d][3])))); \
        }                                                                           \
    }

        COMPUTE(0, j)
        COMPUTE(1, j + 16)
        COMPUTE(2, j + 32)
        COMPUTE(3, j + 48)
        if (j < 11) {
            COMPUTE(4, j + 64)
        }
#undef COMPUTE

        // ---- issue NEXT tile's x loads into the same regs (last use above);
        //      they stay in flight through the DPP reduce + both barriers ----
        if (tt + 1 < NT) {
            const int l0n = (t + 1) * TOUT - 3;
#pragma unroll
            for (int rr = 0; rr < 4; ++rr) {
                const int l  = l0n + lr + rr;
                const int lc = l < 0 ? 0 : (l >= LL ? LL - 1 : l);
                const float4* xr = (const float4*)(xbb + (size_t)lc * EE);
#pragma unroll
                for (int k = 0; k < 5; ++k) {
                    const int c = (k == 4) ? ((j < 11) ? (j + 64) : 74) : (j + 16 * k);
                    xall[k][rr] = xr[c];
                }
            }
        }

        // ---- VALU-only 16-lane reduction (no LDS swizzles) ----
#pragma unroll
        for (int d = 0; d < NJ; ++d)
#pragma unroll
            for (int rr = 0; rr < 4; ++rr) acc[d][rr] = red16(acc[d][rr]);

        // lane j == rr stores row lr+rr into LDS (zeroed if out-of-range)
#pragma unroll
        for (int rr = 0; rr < 4; ++rr) {
            if (j == rr) {
#pragma unroll
                for (int d = 0; d < NJ; ++d) dlds[lr + rr][d] = acc[d][rr] * vf[rr];
            }
        }

        lds_fence_barrier();   // publish dlds; x loads still in flight

        // ---- epilogue: wave w (0..2) handles branch w, lanes 0..55 ----
        if (wave < 3 && lane < TOUT) {
            const int lo = t * TOUT + lane;
            if (lo < LL) {
                const int c = lane + 3;
                const int r = b * LL + lo;

                if (wave == 0) {
                    float pre = 0.0f;
#pragma unroll
                    for (int tp = 0; tp < 3; ++tp) pre += dlds[c + tp - 1][tp];
                    const float s = 1.0f / (1.0f + expf(-(pre + ab3[0])));
                    out[r] = tanhf(s * dlds[c][3] + cb3[0]);
                } else if (wave == 1) {
                    float pre = 0.0f;
#pragma unroll
                    for (int tp = 0; tp < 5; ++tp) pre += dlds[c + tp - 2][4 + tp];
                    const float s = 1.0f / (1.0f + expf(-(pre + ab5[0])));
                    out[NROWS + r] = tanhf(s * dlds[c][9] + cb5[0]);
                } else {
                    float pre = 0.0f;
#pragma unroll
                    for (int tp = 0; tp < 7; ++tp) pre += dlds[c + tp - 3][10 + tp];
                    const float s = 1.0f / (1.0f + expf(-(pre + ab7[0])));
                    out[2 * NROWS + r] = tanhf(s * dlds[c][17] + cb7[0]);
                }
            }
        }

        lds_fence_barrier();   // dlds consumed; safe to overwrite next tile
    }
}

extern "C" void kernel_launch(void* const* d_in, const int* in_sizes, int n_in,
                              void* d_out, int out_size, void* d_ws, size_t ws_size,
                              hipStream_t stream) {
    const float* x   = (const float*)d_in[0];
    const float* aw3 = (const float*)d_in[1];
    const float* ab3 = (const float*)d_in[2];
    const float* cw3 = (const float*)d_in[3];
    const float* cb3 = (const float*)d_in[4];
    const float* aw5 = (const float*)d_in[5];
    const float* ab5 = (const float*)d_in[6];
    const float* cw5 = (const float*)d_in[7];
    const float* cb5 = (const float*)d_in[8];
    const float* aw7 = (const float*)d_in[9];
    const float* ab7 = (const float*)d_in[10];
    const float* cw7 = (const float*)d_in[11];
    const float* cb7 = (const float*)d_in[12];

    float* out = (float*)d_out;  // [out3 | out5 | out7]

    // 256 batches x 3 tile-groups; 768 blocks, ~3 resident/CU, weights staged
    // once per block, 3 tiles pipelined per block
    fused_kernel<<<BB * GRP, 256, 0, stream>>>(
        x, aw3, ab3, cw3, cb3, aw5, ab5, cw5, cb5, aw7, ab7, cw7, cb7, out);
}